// Round 7
// baseline (160.537 us; speedup 1.0000x reference)
//
#include <hip/hip_runtime.h>
#include <math.h>

namespace {

constexpr int PN = 131072;
constexpr int SN = 64;
constexpr int EH = 512;
constexpr int EW = 1024;
constexpr int KP = 4;                       // points per wave
constexpr float SPI = 162.97466172610083f;  // 512/pi

struct F3 { float x, y, z; };

__device__ __forceinline__ float dot3(F3 a, F3 b) { return a.x*b.x + a.y*b.y + a.z*b.z; }
__device__ __forceinline__ F3 cross3(F3 a, F3 b) {
    return F3{a.y*b.z - a.z*b.y, a.z*b.x - a.x*b.z, a.x*b.y - a.y*b.x};
}
__device__ __forceinline__ float clampf(float x, float lo, float hi) {
    return fminf(fmaxf(x, lo), hi);
}
__device__ __forceinline__ F3 norm3(F3 a) {
    float l2 = a.x*a.x + a.y*a.y + a.z*a.z;
    float inv = __builtin_amdgcn_rsqf(fmaxf(l2, 1e-24f));
    return F3{a.x*inv, a.y*inv, a.z*inv};
}
__device__ __forceinline__ float smithf(float alpha, float c) {
    float a2 = alpha*alpha;
    float den = c + __builtin_amdgcn_sqrtf(a2 + (1.0f - a2)*c*c);
    return 2.0f*c*__builtin_amdgcn_rcpf(den);
}

// atan2 via degree-11 odd minimax (abs err ~1e-6 rad)
__device__ __forceinline__ float fast_atan2(float y, float x) {
    float ax = fabsf(x), ay = fabsf(y);
    float mx = fmaxf(ax, ay), mn = fminf(ax, ay);
    float a = mn * __builtin_amdgcn_rcpf(mx);
    if (mx == 0.0f) a = 0.0f;
    float s = a*a;
    float p = fmaf(s, -0.01172120f, 0.05265332f);
    p = fmaf(s, p, -0.11643287f);
    p = fmaf(s, p,  0.19354346f);
    p = fmaf(s, p, -0.33262347f);
    p = fmaf(s, p,  0.99997726f);
    float r = p * a;
    if (ay > ax)  r = 1.57079632679f - r;
    if (x < 0.0f) r = 3.14159265359f - r;
    return copysignf(r, y);
}

// acos via sqrt*poly (abs err ~1e-6 rad); x pre-clamped to [-1,1]
__device__ __forceinline__ float fast_acos(float x) {
    float ax = fabsf(x);
    float p = fmaf(ax, -0.0012624911f, 0.0066700901f);
    p = fmaf(ax, p, -0.0170881256f);
    p = fmaf(ax, p,  0.0308918810f);
    p = fmaf(ax, p, -0.0501743046f);
    p = fmaf(ax, p,  0.0889789874f);
    p = fmaf(ax, p, -0.2145988016f);
    p = fmaf(ax, p,  1.5707963050f);
    float s = __builtin_amdgcn_sqrtf(fmaxf(1.0f - ax, 0.0f));
    float r = s * p;
    return (x >= 0.0f) ? r : 3.14159265359f - r;
}

// lat-long uv -> two row-pair texel indices + weights + border flags
__device__ __forceinline__ void env_addr(F3 d, int& i0, int& i1,
                                         float& wx, float& wy,
                                         bool& at_l, bool& at_r) {
    float t  = fast_atan2(d.x, -d.z);
    float vv = fast_acos(clampf(d.y, -1.0f, 1.0f));
    float x = fmaf(t,  SPI, 511.5f);   // u*W - 0.5
    float y = fmaf(vv, SPI, -0.5f);    // v*H - 0.5
    float x0f = floorf(x), y0f = floorf(y);
    wx = x - x0f; wy = y - y0f;
    int ix = (int)x0f, iy = (int)y0f;
    int xb = min(max(ix, 0), EW - 2);          // pair base: texels xb, xb+1
    int y0 = min(max(iy, 0), EH - 1);
    int y1 = min(max(iy + 1, 0), EH - 1);
    at_l = ix < 0;          // both taps -> pair lo
    at_r = ix >= EW - 1;    // both taps -> pair hi
    i0 = (y0 << 10) + xb;
    i1 = (y1 << 10) + xb;
}

// RGB9E5: value = mant * 2^(e-24); accumulate w * texel into acc
__device__ __forceinline__ void rgb9e5_addmul(unsigned int v, float w, F3& acc) {
    float scale = __uint_as_float(((v >> 27) + 103u) << 23);  // 2^(e-24)
    float ws = w * scale;
    acc.x = fmaf((float)(v & 511u), ws, acc.x);
    acc.y = fmaf((float)((v >> 9) & 511u), ws, acc.y);
    acc.z = fmaf((float)((v >> 18) & 511u), ws, acc.z);
}

__device__ __forceinline__ F3 env_blend9(uint2 r0, uint2 r1, float wx, float wy,
                                         bool at_l, bool at_r) {
    unsigned int t00 = at_r ? r0.y : r0.x;
    unsigned int t01 = at_l ? r0.x : r0.y;
    unsigned int t10 = at_r ? r1.y : r1.x;
    unsigned int t11 = at_l ? r1.x : r1.y;
    float w00 = (1.0f - wx)*(1.0f - wy);
    float w01 = wx*(1.0f - wy);
    float w10 = (1.0f - wx)*wy;
    float w11 = wx*wy;
    F3 acc{0.0f, 0.0f, 0.0f};
    rgb9e5_addmul(t00, w00, acc);
    rgb9e5_addmul(t01, w01, acc);
    rgb9e5_addmul(t10, w10, acc);
    rgb9e5_addmul(t11, w11, acc);
    return acc;
}

// ---- wave64 sum via DPP; total lands in lane 63 (no final broadcast) ----
template<int CTRL, int ROW_MASK, bool BC>
__device__ __forceinline__ float dpp_add_step(float x) {
    int ti = __builtin_amdgcn_update_dpp(0, __float_as_int(x), CTRL, ROW_MASK, 0xf, BC);
    return x + __int_as_float(ti);
}
__device__ __forceinline__ float wave_sum63(float x) {
    x = dpp_add_step<0x111, 0xf, true >(x);  // row_shr:1 (0-fill)
    x = dpp_add_step<0x112, 0xf, true >(x);  // row_shr:2
    x = dpp_add_step<0x114, 0xf, true >(x);  // row_shr:4
    x = dpp_add_step<0x118, 0xf, true >(x);  // row_shr:8  -> lane15 of each row = row sum
    x = dpp_add_step<0x142, 0xa, false>(x);  // row_bcast15 into rows 1,3
    x = dpp_add_step<0x143, 0xc, false>(x);  // row_bcast31 into rows 2,3 -> lane63 = total
    return x;
}

__global__ void relayout_kernel(const float* __restrict__ img, unsigned int* __restrict__ tex) {
    int i = blockIdx.x*blockDim.x + threadIdx.x;
    const int HW = EH*EW;
    if (i < HW) {
        float r = img[i], g = img[HW + i], b = img[2*HW + i];
        float m = fmaxf(fmaxf(r, g), b);
        int es = min(max((int)(__float_as_uint(m) >> 23) - 111, 0), 31);
        float sc = __uint_as_float((unsigned int)(151 - es) << 23);   // 2^(24-es)
        unsigned int R = min(511u, (unsigned int)rintf(r*sc));
        unsigned int G = min(511u, (unsigned int)rintf(g*sc));
        unsigned int B = min(511u, (unsigned int)rintf(b*sc));
        tex[i] = ((unsigned int)es << 27) | (B << 18) | (G << 9) | R;
    }
}

template<bool TEX>
__global__ __launch_bounds__(256) void ibl_kernel(
    const float* __restrict__ emap, const unsigned int* __restrict__ tex,
    const float* __restrict__ view_dir, const float* __restrict__ normal,
    const float* __restrict__ albedo, const float* __restrict__ rough_,
    const float* __restrict__ metal_, const float* __restrict__ u1_,
    const float* __restrict__ u2_, const float* __restrict__ uc_,
    const float* __restrict__ vc_, float* __restrict__ out)
{
    int lane = threadIdx.x & 63;
    int wid  = (blockIdx.x << 2) + (threadIdx.x >> 6);     // wave id
    int p0   = __builtin_amdgcn_readfirstlane(wid * KP);   // KP points per wave, uniform

    // ---- streamed per-sample inputs (non-temporal; keep texture L2-resident) ----
    float U1[KP], U2[KP], UC[KP], VC[KP];
    F3 v[KP], n[KP], alb[KP];
    float alpha[KP], metal[KP];
    #pragma unroll
    for (int k = 0; k < KP; ++k) {
        int p = p0 + k;
        size_t si = (size_t)p*SN + lane;
        U1[k] = __builtin_nontemporal_load(u1_ + si);
        U2[k] = __builtin_nontemporal_load(u2_ + si);
        UC[k] = __builtin_nontemporal_load(uc_ + si);
        VC[k] = __builtin_nontemporal_load(vc_ + si);
        v[k]   = F3{view_dir[3*p], view_dir[3*p+1], view_dir[3*p+2]};
        n[k]   = F3{normal[3*p],   normal[3*p+1],   normal[3*p+2]};
        alb[k] = F3{albedo[3*p],   albedo[3*p+1],   albedo[3*p+2]};
        float rg = rough_[p];
        alpha[k] = rg*rg;
        metal[k] = metal_[p];
    }

    // ---- per-point frames (reuse squared norms; degen select overrides inf) ----
    F3 t[KP], b[KP];
    #pragma unroll
    for (int k = 0; k < KP; ++k) {
        float nx2nz2 = n[k].x*n[k].x + n[k].z*n[k].z;
        float invt = __builtin_amdgcn_rsqf(nx2nz2);
        if (nx2nz2 <= 0.0f) t[k] = F3{1.0f, 0.0f, 0.0f};
        else                t[k] = F3{n[k].z*invt, 0.0f, -n[k].x*invt};
        b[k] = cross3(n[k], t[k]);   // unit to ~1e-7
    }

    // ---- diffuse dirs: short chain, issue gathers FIRST ----
    uint2 dr0[KP], dr1[KP];
    float dwx[KP], dwy[KP];
    bool d_l[KP], d_r[KP];
    F3 ld[KP];
    #pragma unroll
    for (int k = 0; k < KP; ++k) {
        float sph = __builtin_amdgcn_sinf(UC[k]);
        float cph = __builtin_amdgcn_cosf(UC[k]);
        float ct = __builtin_amdgcn_sqrtf(VC[k]);
        float st = __builtin_amdgcn_sqrtf(fmaxf(1.0f - VC[k], 0.0f));
        F3 ldl = F3{cph*st, sph*st, ct};
        ld[k] = F3{t[k].x*ldl.x + b[k].x*ldl.y + n[k].x*ldl.z,
                   t[k].y*ldl.x + b[k].y*ldl.y + n[k].y*ldl.z,
                   t[k].z*ldl.x + b[k].z*ldl.y + n[k].z*ldl.z};
        if (TEX) {
            int i0, i1;
            env_addr(ld[k], i0, i1, dwx[k], dwy[k], d_l[k], d_r[k]);
            dr0[k] = *reinterpret_cast<const uint2*>(tex + i0);
            dr1[k] = *reinterpret_cast<const uint2*>(tex + i1);
        }
    }

    // ---- spec chains (VALU hides diffuse-load latency) ----
    uint2 sr0[KP], sr1[KP];
    float swx[KP], swy[KP];
    bool s_l[KP], s_r[KP];
    F3 light[KP];
    float sv_ratio[KP];
    #pragma unroll
    for (int k = 0; k < KP; ++k) {
        F3 vl = F3{dot3(t[k], v[k]), dot3(b[k], v[k]), dot3(n[k], v[k])};
        float ndv = clampf(vl.z, 0.0f, 1.0f);
        float s_ndv = smithf(alpha[k], ndv);
        // smith() in [0,1] -> ratio s_ndv/clip(s_ndv,1e-10,1) is 1 except degenerate
        sv_ratio[k] = (s_ndv >= 1e-10f) ? 1.0f : s_ndv * 1e10f;

        F3 vh = norm3(F3{vl.x*alpha[k], vl.y*alpha[k], vl.z});
        F3 b1;
        float l2d = vh.x*vh.x + vh.y*vh.y;
        float invb = __builtin_amdgcn_rsqf(l2d);
        if (l2d <= 0.0f) b1 = F3{1.0f, 0.0f, 0.0f};
        else             b1 = F3{-vh.y*invb, vh.x*invb, 0.0f};
        F3 b2 = cross3(vh, b1);
        float sfac = 0.5f*(1.0f + vh.z);

        float r = __builtin_amdgcn_sqrtf(U1[k]);
        float sth = __builtin_amdgcn_sinf(U2[k]);
        float cth = __builtin_amdgcn_cosf(U2[k]);
        float t1 = r*cth;
        float t2 = r*sth;
        t2 = (1.0f - sfac)*__builtin_amdgcn_sqrtf(fmaxf(1.0f - t1*t1, 0.0f)) + sfac*t2;
        float t3 = __builtin_amdgcn_sqrtf(clampf(1.0f - t1*t1 - t2*t2, 0.0f, 1.0f));
        F3 mh = F3{t1*b1.x + t2*b2.x + t3*vh.x,
                   t1*b1.y + t2*b2.y + t3*vh.y,
                   t1*b1.z + t2*b2.z + t3*vh.z};
        F3 ml = norm3(F3{mh.x*alpha[k], mh.y*alpha[k], mh.z});
        F3 m = F3{t[k].x*ml.x + b[k].x*ml.y + n[k].x*ml.z,
                  t[k].y*ml.x + b[k].y*ml.y + n[k].y*ml.z,
                  t[k].z*ml.x + b[k].z*ml.y + n[k].z*ml.z};
        float idm = dot3(v[k], m);
        light[k] = F3{fmaf(2.0f*idm, m.x, -v[k].x),
                      fmaf(2.0f*idm, m.y, -v[k].y),
                      fmaf(2.0f*idm, m.z, -v[k].z)};   // unit reflect of unit v
        if (TEX) {
            int i0, i1;
            env_addr(light[k], i0, i1, swx[k], swy[k], s_l[k], s_r[k]);
            sr0[k] = *reinterpret_cast<const uint2*>(tex + i0);
            sr1[k] = *reinterpret_cast<const uint2*>(tex + i1);
        }
    }

    // ---- shading scalars (hide spec-load latency) ----
    float fresc[KP];   // gs
    float om5[KP];
    #pragma unroll
    for (int k = 0; k < KP; ++k) {
        // hdv = dot(normalize(v+l), v) == sqrt((1 + v.l)/2) for unit v,l
        float c = dot3(v[k], light[k]);
        float hdv = __builtin_amdgcn_sqrtf(clampf(0.5f + 0.5f*c, 0.0f, 1.0f));
        float ndl = clampf(dot3(n[k], light[k]), 0.0f, 1.0f);
        float s_ndl = smithf(alpha[k], ndl);
        fresc[k] = sv_ratio[k] * s_ndl;
        float om = 1.0f - hdv;
        float om2 = om*om;
        om5[k] = om2*om2*om;
    }

    // ---- blends + reduce + output ----
    #pragma unroll
    for (int k = 0; k < KP; ++k) {
        F3 rad, radd;
        if (TEX) {
            radd = env_blend9(dr0[k], dr1[k], dwx[k], dwy[k], d_l[k], d_r[k]);
            rad  = env_blend9(sr0[k], sr1[k], swx[k], swy[k], s_l[k], s_r[k]);
        } else {
            const int HW = EH*EW;
            #pragma unroll
            for (int pass = 0; pass < 2; ++pass) {
                F3 d = pass ? light[k] : ld[k];
                int i0, i1; float wx, wy; bool atl, atr;
                env_addr(d, i0, i1, wx, wy, atl, atr);
                int x0 = atr ? 1 : 0, x1 = atl ? 0 : 1;
                F3 o;
                float* po = &o.x;
                #pragma unroll
                for (int c = 0; c < 3; ++c) {
                    const float* pl = emap + c*HW;
                    float v00 = pl[i0 + x0], v01 = pl[i0 + x1];
                    float v10 = pl[i1 + x0], v11 = pl[i1 + x1];
                    float rr0 = fmaf(wx, v01 - v00, v00);
                    float rr1 = fmaf(wx, v11 - v10, v10);
                    po[c] = fmaf(wy, rr1 - rr0, rr0);
                }
                if (pass) rad = o; else radd = o;
            }
        }
        float gs = fresc[k];
        float mt = metal[k];
        F3 f0 = F3{mt*alb[k].x + (1.0f - mt)*0.04f,
                   mt*alb[k].y + (1.0f - mt)*0.04f,
                   mt*alb[k].z + (1.0f - mt)*0.04f};
        F3 kd = F3{alb[k].x*(1.0f - mt), alb[k].y*(1.0f - mt), alb[k].z*(1.0f - mt)};
        F3 acc;
        acc.x = fmaf((f0.x + (1.0f - f0.x)*om5[k])*gs, rad.x, radd.x*kd.x);
        acc.y = fmaf((f0.y + (1.0f - f0.y)*om5[k])*gs, rad.y, radd.y*kd.y);
        acc.z = fmaf((f0.z + (1.0f - f0.z)*om5[k])*gs, rad.z, radd.z*kd.z);

        float sx = wave_sum63(acc.x);
        float sy = wave_sum63(acc.y);
        float sz = wave_sum63(acc.z);

        if (lane == 63) {
            const float inv_s = 1.0f/(float)SN;
            int p = p0 + k;
            __builtin_nontemporal_store(sx*inv_s, out + 3*p + 0);
            __builtin_nontemporal_store(sy*inv_s, out + 3*p + 1);
            __builtin_nontemporal_store(sz*inv_s, out + 3*p + 2);
        }
    }
}

} // anonymous namespace

extern "C" void kernel_launch(void* const* d_in, const int* in_sizes, int n_in,
                              void* d_out, int out_size, void* d_ws, size_t ws_size,
                              hipStream_t stream) {
    const float* emap     = (const float*)d_in[0];
    const float* view_dir = (const float*)d_in[1];
    const float* normal   = (const float*)d_in[2];
    const float* albedo   = (const float*)d_in[3];
    const float* rough    = (const float*)d_in[4];
    const float* metal    = (const float*)d_in[5];
    const float* u1       = (const float*)d_in[6];
    const float* u2       = (const float*)d_in[7];
    const float* uc       = (const float*)d_in[8];
    const float* vc       = (const float*)d_in[9];
    float* out            = (float*)d_out;

    const int HW = EH*EW;
    const size_t tex_bytes = (size_t)HW*sizeof(unsigned int);
    const int main_blocks = PN/(4*KP);   // 4 waves/block x KP points/wave

    if (ws_size >= tex_bytes) {
        unsigned int* tex = (unsigned int*)d_ws;
        relayout_kernel<<<(HW + 255)/256, 256, 0, stream>>>(emap, tex);
        ibl_kernel<true><<<main_blocks, 256, 0, stream>>>(
            emap, tex, view_dir, normal, albedo, rough, metal, u1, u2, uc, vc, out);
    } else {
        ibl_kernel<false><<<main_blocks, 256, 0, stream>>>(
            emap, nullptr, view_dir, normal, albedo, rough, metal, u1, u2, uc, vc, out);
    }
}